// Round 1
// baseline (7470.966 us; speedup 1.0000x reference)
//
#include <hip/hip_runtime.h>
#include <hip/hip_bf16.h>
#include <math.h>

// Problem constants (B=1, S=2048, D=1024, E=8, K=2, FF=4096)
#define T_      2048
#define D_      1024
#define E_      8
#define FF_     4096
#define TM_     16                  // tokens per tile
#define FSPLIT_ 4                   // FF range splits per (expert, tile)
#define FRANGE_ (FF_ / FSPLIT_)     // 1024
#define FC_     64                  // FF chunk per phase-1/2 round
#define TILES_  (T_ / TM_)          // 128 (capacity tiles; worst case all tokens on one expert)

// ---------------------------------------------------------------------------
// Router: logits = h @ gate_w^T, write raw logits, top-2 + renorm weights,
// atomic-append (token, weight) into per-expert lists.
// Note: softmax denom cancels in top-2 renormalization: w0 = 1/(1+exp(l1-l0)).
// ---------------------------------------------------------------------------
__global__ __launch_bounds__(64) void router_kernel(
    const float* __restrict__ h, const float* __restrict__ gw,
    float* __restrict__ logits, int* __restrict__ counts,
    int* __restrict__ lists, float* __restrict__ wlist)
{
    int t = blockIdx.x;
    int lane = threadIdx.x;
    const float* hrow = h + (size_t)t * D_;
    float part[E_];
#pragma unroll
    for (int e = 0; e < E_; ++e) part[e] = 0.f;
    for (int d = lane; d < D_; d += 64) {
        float hv = hrow[d];
#pragma unroll
        for (int e = 0; e < E_; ++e) part[e] += hv * gw[e * D_ + d];
    }
#pragma unroll
    for (int e = 0; e < E_; ++e) {
        float v = part[e];
#pragma unroll
        for (int off = 32; off > 0; off >>= 1) v += __shfl_down(v, off, 64);
        part[e] = v;
    }
    if (lane == 0) {
        float* lo = logits + (size_t)t * E_;
#pragma unroll
        for (int e = 0; e < E_; ++e) lo[e] = part[e];
        // top-2 (strict > keeps lowest index on ties, matching lax.top_k)
        int i0 = 0;
#pragma unroll
        for (int e = 1; e < E_; ++e) if (part[e] > part[i0]) i0 = e;
        int i1 = (i0 == 0) ? 1 : 0;
#pragma unroll
        for (int e = 0; e < E_; ++e)
            if (e != i0 && part[e] > part[i1]) i1 = e;
        float w1v = expf(part[i1] - part[i0]);   // relative to max => w0=1
        float s = 1.0f + w1v;
        float w0 = 1.0f / s;
        float w1n = w1v / s;
        int p0 = atomicAdd(&counts[i0], 1);
        lists[i0 * T_ + p0] = t; wlist[i0 * T_ + p0] = w0;
        int p1 = atomicAdd(&counts[i1], 1);
        lists[i1 * T_ + p1] = t; wlist[i1 * T_ + p1] = w1n;
    }
}

// ---------------------------------------------------------------------------
// Fused expert MLP over gathered token tiles.
// Block = (expert e, FF-split fs, token tile). 256 threads.
// Phase 1: up/gate GEMM (h rows staged in LDS), silu*gate -> LDS inter chunk.
// Phase 2: out-accumulate inter @ w2^T chunk into per-thread register tile.
// Epilogue: weighted atomicAdd into zero-initialized out.
// ---------------------------------------------------------------------------
__global__ __launch_bounds__(256) void moe_kernel(
    const float* __restrict__ h, const float* __restrict__ w1,
    const float* __restrict__ w3, const float* __restrict__ w2,
    const int* __restrict__ counts, const int* __restrict__ lists,
    const float* __restrict__ wlist, float* __restrict__ out)
{
    // bid = ((e*FSPLIT)+fs)*TILES + tile  (same-(e,fs) blocks adjacent -> L2 reuse)
    int bid = blockIdx.x;
    int tile = bid % TILES_;
    int efs  = bid / TILES_;
    int fs   = efs % FSPLIT_;
    int e    = efs / FSPLIT_;

    int ne = counts[e];
    if (tile * TM_ >= ne) return;   // uniform exit, no barrier hazard

    __shared__ float4 hs4[TM_ * (D_ / 4)];      // 64 KB: staged h rows
    __shared__ float4 inter4[TM_ * (FC_ / 4)];  // 4 KB: silu(up)*gate chunk
    __shared__ int   stok[TM_];
    __shared__ float swgt[TM_];

    int tid = threadIdx.x;
    if (tid < TM_) {
        int idx = tile * TM_ + tid;
        if (idx < ne) { stok[tid] = lists[e * T_ + idx]; swgt[tid] = wlist[e * T_ + idx]; }
        else          { stok[tid] = 0;                   swgt[tid] = 0.f; }
    }
    __syncthreads();

    const float4* h4 = (const float4*)h;
    for (int i = tid; i < TM_ * (D_ / 4); i += 256) {
        int m = i >> 8;     // / 256 float4 per row
        int c = i & 255;
        hs4[i] = h4[(size_t)stok[m] * (D_ / 4) + c];
    }
    __syncthreads();

    int f  = tid & 63;       // phase-1 FF lane
    int mg = tid >> 6;       // wave id -> token group
    int m0 = mg * 4;
    int d0 = tid * 4;        // phase-2 output columns d0..d0+3

    float acc[TM_][4];
#pragma unroll
    for (int m = 0; m < TM_; ++m)
#pragma unroll
        for (int j = 0; j < 4; ++j) acc[m][j] = 0.f;

    int fbase = fs * FRANGE_;
    for (int ch = 0; ch < FRANGE_ / FC_; ++ch) {
        int fbg = fbase + ch * FC_;

        // ---- phase 1: up/gate dot products over D (h from LDS, w from global)
        const float4* w1r = (const float4*)(w1 + ((size_t)e * FF_ + fbg + f) * D_);
        const float4* w3r = (const float4*)(w3 + ((size_t)e * FF_ + fbg + f) * D_);
        float up[4] = {0.f, 0.f, 0.f, 0.f}, gt[4] = {0.f, 0.f, 0.f, 0.f};
        for (int c = 0; c < D_ / 4; ++c) {
            float4 a = w1r[c];
            float4 b = w3r[c];
#pragma unroll
            for (int j = 0; j < 4; ++j) {
                float4 hv = hs4[(m0 + j) * (D_ / 4) + c];   // wave-broadcast
                up[j] += hv.x * a.x + hv.y * a.y + hv.z * a.z + hv.w * a.w;
                gt[j] += hv.x * b.x + hv.y * b.y + hv.z * b.z + hv.w * b.w;
            }
        }
        __syncthreads();    // prior phase-2 readers done with inter4
        {
            float* interf = (float*)inter4;
#pragma unroll
            for (int j = 0; j < 4; ++j) {
                float u  = up[j];
                float sg = 1.f / (1.f + expf(-u));
                interf[(m0 + j) * FC_ + f] = u * sg * gt[j];
            }
        }
        __syncthreads();    // inter chunk ready

        // ---- phase 2: acc[m][j] += inter[m][:] . w2[d0+j][fbg..fbg+63]
        const float4* w2r = (const float4*)(w2 + ((size_t)e * D_ + d0) * FF_ + fbg);
#pragma unroll 4
        for (int f4 = 0; f4 < FC_ / 4; ++f4) {
            float4 wv0 = w2r[f4];
            float4 wv1 = w2r[(FF_ / 4) + f4];
            float4 wv2 = w2r[2 * (FF_ / 4) + f4];
            float4 wv3 = w2r[3 * (FF_ / 4) + f4];
#pragma unroll
            for (int m = 0; m < TM_; ++m) {
                float4 iv = inter4[m * (FC_ / 4) + f4];     // wave-broadcast
                acc[m][0] += iv.x * wv0.x + iv.y * wv0.y + iv.z * wv0.z + iv.w * wv0.w;
                acc[m][1] += iv.x * wv1.x + iv.y * wv1.y + iv.z * wv1.z + iv.w * wv1.w;
                acc[m][2] += iv.x * wv2.x + iv.y * wv2.y + iv.z * wv2.z + iv.w * wv2.w;
                acc[m][3] += iv.x * wv3.x + iv.y * wv3.y + iv.z * wv3.z + iv.w * wv3.w;
            }
        }
    }

    // ---- epilogue: weighted accumulate into out (<=8 fp32 atomics/element total)
#pragma unroll
    for (int m = 0; m < TM_; ++m) {
        float wm = swgt[m];
        if (wm != 0.f) {
            float* op = out + (size_t)stok[m] * D_ + d0;
            atomicAdd(op + 0, wm * acc[m][0]);
            atomicAdd(op + 1, wm * acc[m][1]);
            atomicAdd(op + 2, wm * acc[m][2]);
            atomicAdd(op + 3, wm * acc[m][3]);
        }
    }
}

extern "C" void kernel_launch(void* const* d_in, const int* in_sizes, int n_in,
                              void* d_out, int out_size, void* d_ws, size_t ws_size,
                              hipStream_t stream)
{
    const float* h  = (const float*)d_in[0];   // [1,2048,1024]
    const float* gw = (const float*)d_in[1];   // [8,1024]
    const float* w1 = (const float*)d_in[2];   // [8,4096,1024]
    const float* w3 = (const float*)d_in[3];   // [8,4096,1024]
    const float* w2 = (const float*)d_in[4];   // [8,1024,4096]

    float* out    = (float*)d_out;             // [2048*1024] then logits
    float* logits = out + (size_t)T_ * D_;     // [2048*8]

    char* ws = (char*)d_ws;
    int*   counts = (int*)ws;                          // 32 B (pad to 128)
    int*   lists  = (int*)(ws + 128);                  // E*T ints  = 64 KB
    float* wlist  = (float*)(ws + 128 + E_ * T_ * 4);  // E*T floats = 64 KB

    hipMemsetAsync(counts, 0, 128, stream);
    hipMemsetAsync(out, 0, (size_t)T_ * D_ * sizeof(float), stream);

    router_kernel<<<T_, 64, 0, stream>>>(h, gw, logits, counts, lists, wlist);
    moe_kernel<<<E_ * FSPLIT_ * TILES_, 256, 0, stream>>>(h, w1, w3, w2,
                                                          counts, lists, wlist, out);
}

// Round 2
// 3003.307 us; speedup vs baseline: 2.4876x; 2.4876x over previous
//
#include <hip/hip_runtime.h>
#include <hip/hip_bf16.h>
#include <math.h>

// Problem constants (B=1, S=2048, D=1024, E=8, K=2, FF=4096)
#define T_      2048
#define D_      1024
#define E_      8
#define FF_     4096
#define M_      32                  // tokens per tile
#define FSPLIT_ 4                   // FF range splits per (expert, tile)
#define FRANGE_ (FF_ / FSPLIT_)     // 1024
#define FC_     64                  // FF chunk per phase-1/2 round
#define NCHUNK_ (FRANGE_ / FC_)     // 16
#define TILESCAP_ (T_ / M_)         // 64 capacity tiles per expert
#define HSP_    1032                // padded bf16 row stride for hs (16B-aligned, conflict-free)
#define FCP_    72                  // padded bf16 row stride for inter

typedef __attribute__((ext_vector_type(8))) short  bf16x8;   // MFMA A/B frag
typedef __attribute__((ext_vector_type(4))) float  f32x4;    // MFMA C/D frag
typedef __attribute__((ext_vector_type(8))) float  f32x8;
typedef __attribute__((ext_vector_type(8))) __bf16 b16x8;
typedef __attribute__((ext_vector_type(4))) __bf16 b16x4;
typedef __attribute__((ext_vector_type(4))) float  f32x4v;

static __device__ inline bf16x8 cvt8(float4 a, float4 b) {
    f32x8 x;
    x[0] = a.x; x[1] = a.y; x[2] = a.z; x[3] = a.w;
    x[4] = b.x; x[5] = b.y; x[6] = b.z; x[7] = b.w;
    b16x8 c = __builtin_convertvector(x, b16x8);   // RNE, lets compiler use pk-cvt
    return *(bf16x8*)&c;
}

// ---------------------------------------------------------------------------
// Router (fp32): logits, top-2 + renorm, per-expert (token, weight) lists.
// Softmax denominator cancels in top-2 renorm: w0 = 1/(1+exp(l1-l0)).
// ---------------------------------------------------------------------------
__global__ __launch_bounds__(64) void router_kernel(
    const float* __restrict__ h, const float* __restrict__ gw,
    float* __restrict__ logits, int* __restrict__ counts,
    int* __restrict__ lists, float* __restrict__ wlist)
{
    int t = blockIdx.x;
    int lane = threadIdx.x;
    const float* hrow = h + (size_t)t * D_;
    float part[E_];
#pragma unroll
    for (int e = 0; e < E_; ++e) part[e] = 0.f;
    for (int d = lane; d < D_; d += 64) {
        float hv = hrow[d];
#pragma unroll
        for (int e = 0; e < E_; ++e) part[e] += hv * gw[e * D_ + d];
    }
#pragma unroll
    for (int e = 0; e < E_; ++e) {
        float v = part[e];
#pragma unroll
        for (int off = 32; off > 0; off >>= 1) v += __shfl_down(v, off, 64);
        part[e] = v;
    }
    if (lane == 0) {
        float* lo = logits + (size_t)t * E_;
#pragma unroll
        for (int e = 0; e < E_; ++e) lo[e] = part[e];
        int i0 = 0;
#pragma unroll
        for (int e = 1; e < E_; ++e) if (part[e] > part[i0]) i0 = e;
        int i1 = (i0 == 0) ? 1 : 0;
#pragma unroll
        for (int e = 0; e < E_; ++e)
            if (e != i0 && part[e] > part[i1]) i1 = e;
        float w1v = expf(part[i1] - part[i0]);
        float s = 1.0f + w1v;
        int p0 = atomicAdd(&counts[i0], 1);
        lists[i0 * T_ + p0] = t; wlist[i0 * T_ + p0] = 1.0f / s;
        int p1 = atomicAdd(&counts[i1], 1);
        lists[i1 * T_ + p1] = t; wlist[i1 * T_ + p1] = w1v / s;
    }
}

// ---------------------------------------------------------------------------
// Fused MFMA expert MLP. Block = (expert e, FF-split fs, 32-token tile).
// 512 threads = 8 waves in a 2(m) x 4(n) grid.
// GEMM1: up/gate[32][FC] = Hs(bf16,LDS) x W1/W3(fp32->bf16 regs), K=1024.
// silu*gate -> bf16 LDS (C-layout -> A-layout round trip).
// GEMM2: acc[32][1024] += inter x W2^T chunk, K=FC.
// Epilogue: weighted fp32 atomicAdd into zeroed out.
// MFMA 16x16x32 bf16 layouts (m89/m91-verified):
//   A: lane holds A[m=lane&15][k=(lane>>4)*8+j]; B: B[k=(lane>>4)*8+j][n=lane&15]
//   C/D: col=lane&15, row=(lane>>4)*4+reg
// ---------------------------------------------------------------------------
__global__ __launch_bounds__(512) void moe_kernel(
    const float* __restrict__ h, const float* __restrict__ w1,
    const float* __restrict__ w3, const float* __restrict__ w2,
    const int* __restrict__ counts, const int* __restrict__ lists,
    const float* __restrict__ wlist, float* __restrict__ out)
{
    int bid  = blockIdx.x;
    int tile = bid % TILESCAP_;
    int fs   = (bid / TILESCAP_) % FSPLIT_;
    int e    = bid / (TILESCAP_ * FSPLIT_);

    int ne = counts[e];
    if (tile * M_ >= ne) return;    // uniform exit before any barrier

    __shared__ __bf16 hs[M_ * HSP_];       // 66 KB staged tokens (bf16, padded)
    __shared__ __bf16 inter[M_ * FCP_];    // 4.6 KB silu(up)*gate chunk
    __shared__ int    stok[M_];
    __shared__ float  swgt[M_];

    int tid  = threadIdx.x;
    int lane = tid & 63;
    int w    = tid >> 6;
    int mg   = w >> 2;      // 0..1 : token half
    int ng   = w & 3;       // 0..3 : n quarter
    int ln   = lane & 15;
    int q    = lane >> 4;   // quad

    if (tid < M_) {
        int idx = tile * M_ + tid;
        if (idx < ne) { stok[tid] = lists[e * T_ + idx]; swgt[tid] = wlist[e * T_ + idx]; }
        else          { stok[tid] = 0;                   swgt[tid] = 0.f; }
    }
    __syncthreads();

    // stage h rows -> bf16 LDS (float4 read, b16x4 = 8B LDS write)
    const float4* h4 = (const float4*)h;
    for (int i = tid; i < M_ * (D_ / 4); i += 512) {
        int row = i >> 8;
        int c4  = i & 255;
        float4 v = h4[(size_t)stok[row] * (D_ / 4) + c4];
        f32x4 vv; vv[0] = v.x; vv[1] = v.y; vv[2] = v.z; vv[3] = v.w;
        b16x4 bv = __builtin_convertvector(vv, b16x4);
        *(b16x4*)&hs[row * HSP_ + c4 * 4] = bv;
    }
    __syncthreads();

    f32x4 acc[16];
#pragma unroll
    for (int nt = 0; nt < 16; ++nt) acc[nt] = (f32x4){0.f, 0.f, 0.f, 0.f};

    int fbase = fs * FRANGE_;
    int arow  = (mg * 16 + ln) * HSP_;     // A-frag row base in hs

    for (int ch = 0; ch < NCHUNK_; ++ch) {
        int fbg = fbase + ch * FC_;

        // ---- GEMM1: up/gate 16x16 tile per wave, K=1024 (32 MFMA k-steps x2)
        const float* w1p = w1 + ((size_t)e * FF_ + fbg + ng * 16 + ln) * D_;
        const float* w3p = w3 + ((size_t)e * FF_ + fbg + ng * 16 + ln) * D_;
        f32x4 upacc = (f32x4){0.f, 0.f, 0.f, 0.f};
        f32x4 gtacc = (f32x4){0.f, 0.f, 0.f, 0.f};
#pragma unroll 2
        for (int kk = 0; kk < 32; ++kk) {
            int ko = kk * 32 + q * 8;
            bf16x8 a = *(bf16x8*)&hs[arow + ko];
            float4 u0 = *(const float4*)(w1p + ko);
            float4 u1 = *(const float4*)(w1p + ko + 4);
            float4 g0 = *(const float4*)(w3p + ko);
            float4 g1 = *(const float4*)(w3p + ko + 4);
            upacc = __builtin_amdgcn_mfma_f32_16x16x32_bf16(a, cvt8(u0, u1), upacc, 0, 0, 0);
            gtacc = __builtin_amdgcn_mfma_f32_16x16x32_bf16(a, cvt8(g0, g1), gtacc, 0, 0, 0);
        }

        __syncthreads();   // previous chunk's GEMM2 done reading inter
        {
            int mrow = mg * 16 + q * 4;
#pragma unroll
            for (int r = 0; r < 4; ++r) {
                float u = upacc[r];
                float g = gtacc[r];
                float val = (u / (1.f + expf(-u))) * g;   // silu(u)*g
                inter[(mrow + r) * FCP_ + ng * 16 + ln] = (__bf16)val;
            }
        }
        __syncthreads();   // inter chunk ready

        // ---- GEMM2: acc[m][d] += inter[m][ff] * w2[d][ff], K=FC (2 k-steps)
        bf16x8 a0 = *(bf16x8*)&inter[(mg * 16 + ln) * FCP_ + q * 8];
        bf16x8 a1 = *(bf16x8*)&inter[(mg * 16 + ln) * FCP_ + 32 + q * 8];
        const float* w2base = w2 + (size_t)e * D_ * FF_ + fbg + q * 8;
#pragma unroll
        for (int nt = 0; nt < 16; ++nt) {
            int d = ng * 256 + nt * 16 + ln;
            const float* w2p = w2base + (size_t)d * FF_;
            float4 p0 = *(const float4*)(w2p);
            float4 p1 = *(const float4*)(w2p + 4);
            float4 p2 = *(const float4*)(w2p + 32);
            float4 p3 = *(const float4*)(w2p + 36);
            acc[nt] = __builtin_amdgcn_mfma_f32_16x16x32_bf16(a0, cvt8(p0, p1), acc[nt], 0, 0, 0);
            acc[nt] = __builtin_amdgcn_mfma_f32_16x16x32_bf16(a1, cvt8(p2, p3), acc[nt], 0, 0, 0);
        }
    }

    // ---- epilogue: weighted atomic accumulate (C/D: row=q*4+r, col=ln)
    int   tok[4]; float wgt[4];
#pragma unroll
    for (int r = 0; r < 4; ++r) {
        int m = mg * 16 + q * 4 + r;
        tok[r] = stok[m];
        wgt[r] = swgt[m];
    }
#pragma unroll
    for (int nt = 0; nt < 16; ++nt) {
        int d = ng * 256 + nt * 16 + ln;
#pragma unroll
        for (int r = 0; r < 4; ++r) {
            if (wgt[r] != 0.f)
                atomicAdd(out + (size_t)tok[r] * D_ + d, wgt[r] * acc[nt][r]);
        }
    }
}

extern "C" void kernel_launch(void* const* d_in, const int* in_sizes, int n_in,
                              void* d_out, int out_size, void* d_ws, size_t ws_size,
                              hipStream_t stream)
{
    const float* h  = (const float*)d_in[0];   // [1,2048,1024]
    const float* gw = (const float*)d_in[1];   // [8,1024]
    const float* w1 = (const float*)d_in[2];   // [8,4096,1024]
    const float* w3 = (const float*)d_in[3];   // [8,4096,1024]
    const float* w2 = (const float*)d_in[4];   // [8,1024,4096]

    float* out    = (float*)d_out;             // [2048*1024] then logits
    float* logits = out + (size_t)T_ * D_;     // [2048*8]

    char* ws = (char*)d_ws;
    int*   counts = (int*)ws;                          // 32 B (pad to 128)
    int*   lists  = (int*)(ws + 128);                  // E*T ints
    float* wlist  = (float*)(ws + 128 + E_ * T_ * 4);  // E*T floats

    hipMemsetAsync(counts, 0, 128, stream);
    hipMemsetAsync(out, 0, (size_t)T_ * D_ * sizeof(float), stream);

    router_kernel<<<T_, 64, 0, stream>>>(h, gw, logits, counts, lists, wlist);
    moe_kernel<<<E_ * FSPLIT_ * TILESCAP_, 512, 0, stream>>>(h, w1, w3, w2,
                                                             counts, lists, wlist, out);
}

// Round 3
// 1263.826 us; speedup vs baseline: 5.9114x; 2.3764x over previous
//
#include <hip/hip_runtime.h>
#include <hip/hip_bf16.h>
#include <math.h>

// Problem constants (B=1, S=2048, D=1024, E=8, K=2, FF=4096)
#define T_      2048
#define D_      1024
#define E_      8
#define FF_     4096
#define M_      64                  // tokens per tile
#define FSPLIT_ 4                   // FF range splits per (expert, tile)
#define FRANGE_ (FF_ / FSPLIT_)     // 1024
#define FC_     128                 // FF chunk per GEMM1/GEMM2 round
#define NCHUNK_ (FRANGE_ / FC_)     // 8
#define TILECAP_ (T_ / M_)          // 32 capacity tiles per expert
#define HSP_    1032                // padded bf16 row stride for hs (16B-aligned)
#define FCP_    136                 // padded bf16 row stride for inter (16B-aligned)

typedef __attribute__((ext_vector_type(8))) short  bf16x8;   // MFMA A/B frag
typedef __attribute__((ext_vector_type(4))) float  f32x4;    // MFMA C/D frag
typedef __attribute__((ext_vector_type(8))) float  f32x8;
typedef __attribute__((ext_vector_type(8))) __bf16 b16x8;
typedef __attribute__((ext_vector_type(4))) __bf16 b16x4;

static __device__ inline bf16x8 cvt8(float4 a, float4 b) {
    f32x8 x;
    x[0] = a.x; x[1] = a.y; x[2] = a.z; x[3] = a.w;
    x[4] = b.x; x[5] = b.y; x[6] = b.z; x[7] = b.w;
    b16x8 c = __builtin_convertvector(x, b16x8);   // RNE, packed cvt
    return *(bf16x8*)&c;
}

// ---------------------------------------------------------------------------
// Router (fp32): logits, top-2 + renorm, per-expert (token, weight) lists.
// Softmax denominator cancels in top-2 renorm: w0 = 1/(1+exp(l1-l0)).
// 4 tokens per 256-thread block (1 wave/token).
// ---------------------------------------------------------------------------
__global__ __launch_bounds__(256) void router_kernel(
    const float* __restrict__ h, const float* __restrict__ gw,
    float* __restrict__ logits, int* __restrict__ counts,
    int* __restrict__ lists, float* __restrict__ wlist)
{
    int t = blockIdx.x * 4 + (threadIdx.x >> 6);
    int lane = threadIdx.x & 63;
    const float* hrow = h + (size_t)t * D_;
    float part[E_];
#pragma unroll
    for (int e = 0; e < E_; ++e) part[e] = 0.f;
    for (int d = lane; d < D_; d += 64) {
        float hv = hrow[d];
#pragma unroll
        for (int e = 0; e < E_; ++e) part[e] += hv * gw[e * D_ + d];
    }
#pragma unroll
    for (int e = 0; e < E_; ++e) {
        float v = part[e];
#pragma unroll
        for (int off = 32; off > 0; off >>= 1) v += __shfl_down(v, off, 64);
        part[e] = v;
    }
    if (lane == 0) {
        float* lo = logits + (size_t)t * E_;
#pragma unroll
        for (int e = 0; e < E_; ++e) lo[e] = part[e];
        int i0 = 0;
#pragma unroll
        for (int e = 1; e < E_; ++e) if (part[e] > part[i0]) i0 = e;
        int i1 = (i0 == 0) ? 1 : 0;
#pragma unroll
        for (int e = 0; e < E_; ++e)
            if (e != i0 && part[e] > part[i1]) i1 = e;
        float w1v = expf(part[i1] - part[i0]);
        float s = 1.0f + w1v;
        int p0 = atomicAdd(&counts[i0], 1);
        lists[i0 * T_ + p0] = t; wlist[i0 * T_ + p0] = 1.0f / s;
        int p1 = atomicAdd(&counts[i1], 1);
        lists[i1 * T_ + p1] = t; wlist[i1 * T_ + p1] = w1v / s;
    }
}

// ---------------------------------------------------------------------------
// Fused MFMA expert MLP. Block = (expert e, FF-split fs, 64-token tile).
// 512 threads = 8 waves; ALL waves split the n-dimension so every B-fragment
// is reused across 4 A-fragments (MFMA:global-load = 2:1).
// bid = tile*32 + (e*4+fs): tiles sharing a weight slice have equal bid%8
// -> same XCD -> L2 temporal reuse (heuristic, correctness-neutral).
// GEMM1: up/gt[64][128] = Hs(LDS bf16) x W1/W3(fp32->bf16), K=1024.
// GEMM2: acc[64][1024] += silu*gate(LDS bf16) x W2^T, K=128 per chunk.
// MFMA 16x16x32 bf16 layouts (m89/m91-verified):
//   A: lane holds A[m=lane&15][k=(lane>>4)*8+j]; B: B[k=(lane>>4)*8+j][n=lane&15]
//   C/D: col=lane&15, row=(lane>>4)*4+reg
// ---------------------------------------------------------------------------
__global__ __launch_bounds__(512, 2) void moe_kernel(
    const float* __restrict__ h, const float* __restrict__ w1,
    const float* __restrict__ w3, const float* __restrict__ w2,
    const int* __restrict__ counts, const int* __restrict__ lists,
    const float* __restrict__ wlist, float* __restrict__ out)
{
    int bid  = blockIdx.x;
    int efs  = bid & 31;
    int tile = bid >> 5;
    int fs   = efs & 3;
    int e    = efs >> 2;

    int ne = counts[e];
    if (tile * M_ >= ne) return;    // uniform exit before any barrier

    __shared__ __bf16 hs[M_ * HSP_];       // 129 KB staged tokens (bf16)
    __shared__ __bf16 inter[M_ * FCP_];    // 17 KB silu(up)*gate chunk
    __shared__ int    stok[M_];
    __shared__ float  swgt[M_];

    int tid  = threadIdx.x;
    int lane = tid & 63;
    int w    = tid >> 6;    // wave id = n-slice owner
    int ln   = lane & 15;
    int q    = lane >> 4;   // quad

    if (tid < M_) {
        int idx = tile * M_ + tid;
        if (idx < ne) { stok[tid] = lists[e * T_ + idx]; swgt[tid] = wlist[e * T_ + idx]; }
        else          { stok[tid] = 0;                   swgt[tid] = 0.f; }
    }
    __syncthreads();

    // stage 64 gathered h rows -> bf16 LDS
    const float4* h4 = (const float4*)h;
    for (int i = tid; i < M_ * (D_ / 4); i += 512) {
        int row = i >> 8;
        int c4  = i & 255;
        float4 v = h4[(size_t)stok[row] * (D_ / 4) + c4];
        f32x4 vv; vv[0] = v.x; vv[1] = v.y; vv[2] = v.z; vv[3] = v.w;
        b16x4 bv = __builtin_convertvector(vv, b16x4);
        *(b16x4*)&hs[row * HSP_ + c4 * 4] = bv;
    }
    __syncthreads();

    f32x4 acc[4][8];
#pragma unroll
    for (int mt = 0; mt < 4; ++mt)
#pragma unroll
        for (int nt = 0; nt < 8; ++nt) acc[mt][nt] = (f32x4){0.f, 0.f, 0.f, 0.f};

    int fbase = fs * FRANGE_;
    for (int ch = 0; ch < NCHUNK_; ++ch) {
        int fbg = fbase + ch * FC_;

        // ---- GEMM1: wave w owns ff rows [fbg+w*16, +16); K=1024 (32 k-steps)
        const float* w1p = w1 + ((size_t)e * FF_ + fbg + w * 16 + ln) * D_;
        const float* w3p = w3 + ((size_t)e * FF_ + fbg + w * 16 + ln) * D_;
        f32x4 up[4], gt[4];
#pragma unroll
        for (int mt = 0; mt < 4; ++mt) {
            up[mt] = (f32x4){0.f, 0.f, 0.f, 0.f};
            gt[mt] = (f32x4){0.f, 0.f, 0.f, 0.f};
        }
#pragma unroll 4
        for (int kk = 0; kk < 32; ++kk) {
            int ko = kk * 32 + q * 8;
            bf16x8 b1 = cvt8(*(const float4*)(w1p + ko), *(const float4*)(w1p + ko + 4));
            bf16x8 b3 = cvt8(*(const float4*)(w3p + ko), *(const float4*)(w3p + ko + 4));
#pragma unroll
            for (int mt = 0; mt < 4; ++mt) {
                bf16x8 a = *(bf16x8*)&hs[(mt * 16 + ln) * HSP_ + ko];
                up[mt] = __builtin_amdgcn_mfma_f32_16x16x32_bf16(a, b1, up[mt], 0, 0, 0);
                gt[mt] = __builtin_amdgcn_mfma_f32_16x16x32_bf16(a, b3, gt[mt], 0, 0, 0);
            }
        }

        __syncthreads();   // previous chunk's GEMM2 done reading inter
#pragma unroll
        for (int mt = 0; mt < 4; ++mt)
#pragma unroll
            for (int r = 0; r < 4; ++r) {
                float u = up[mt][r];
                float g = gt[mt][r];
                float val = (u / (1.f + expf(-u))) * g;   // silu(u)*g
                inter[(mt * 16 + q * 4 + r) * FCP_ + w * 16 + ln] = (__bf16)val;
            }
        __syncthreads();   // inter chunk ready

        // ---- GEMM2: wave w owns d range [w*128, +128); K=FC=128 (4 k-steps)
        const float* w2base = w2 + (size_t)e * D_ * FF_ + fbg;
#pragma unroll
        for (int kk2 = 0; kk2 < 4; ++kk2) {
            int ko = kk2 * 32 + q * 8;
            bf16x8 a[4];
#pragma unroll
            for (int mt = 0; mt < 4; ++mt)
                a[mt] = *(bf16x8*)&inter[(mt * 16 + ln) * FCP_ + ko];
#pragma unroll
            for (int nt = 0; nt < 8; ++nt) {
                int d = w * 128 + nt * 16 + ln;
                const float* w2p = w2base + (size_t)d * FF_ + ko;
                bf16x8 b = cvt8(*(const float4*)w2p, *(const float4*)(w2p + 4));
#pragma unroll
                for (int mt = 0; mt < 4; ++mt)
                    acc[mt][nt] = __builtin_amdgcn_mfma_f32_16x16x32_bf16(a[mt], b, acc[mt][nt], 0, 0, 0);
            }
        }
    }

    // ---- epilogue: weighted atomic accumulate (C/D: row=q*4+r, col=ln)
#pragma unroll
    for (int mt = 0; mt < 4; ++mt) {
#pragma unroll
        for (int r = 0; r < 4; ++r) {
            int m = mt * 16 + q * 4 + r;
            float wgt = swgt[m];
            if (wgt != 0.f) {
                float* op = out + (size_t)stok[m] * D_;
#pragma unroll
                for (int nt = 0; nt < 8; ++nt)
                    atomicAdd(op + w * 128 + nt * 16 + ln, wgt * acc[mt][nt][r]);
            }
        }
    }
}

extern "C" void kernel_launch(void* const* d_in, const int* in_sizes, int n_in,
                              void* d_out, int out_size, void* d_ws, size_t ws_size,
                              hipStream_t stream)
{
    const float* h  = (const float*)d_in[0];   // [1,2048,1024]
    const float* gw = (const float*)d_in[1];   // [8,1024]
    const float* w1 = (const float*)d_in[2];   // [8,4096,1024]
    const float* w3 = (const float*)d_in[3];   // [8,4096,1024]
    const float* w2 = (const float*)d_in[4];   // [8,1024,4096]

    float* out    = (float*)d_out;             // [2048*1024] then logits
    float* logits = out + (size_t)T_ * D_;     // [2048*8]

    char* ws = (char*)d_ws;
    int*   counts = (int*)ws;                          // 32 B (pad to 128)
    int*   lists  = (int*)(ws + 128);                  // E*T ints
    float* wlist  = (float*)(ws + 128 + E_ * T_ * 4);  // E*T floats

    hipMemsetAsync(counts, 0, 128, stream);
    hipMemsetAsync(out, 0, (size_t)T_ * D_ * sizeof(float), stream);

    router_kernel<<<T_ / 4, 256, 0, stream>>>(h, gw, logits, counts, lists, wlist);
    moe_kernel<<<E_ * FSPLIT_ * TILECAP_, 512, 0, stream>>>(h, w1, w3, w2,
                                                            counts, lists, wlist, out);
}